// Round 1
// baseline (572.301 us; speedup 1.0000x reference)
//
#include <hip/hip_runtime.h>

#define NN 50000
#define NE 400000
#define CNN 25000
#define NBINS 1024

// weight offsets (layout from convert_weights)
#define RL1ST 0            // l1s transposed: (192,64), col-contiguous
#define RL1VT 12288        // l1v transposed: (64,64)
#define RL2S  16384        // l2s original (160,32)
#define RL2V  21504        // l2v original (96,32)
#define WTOT  24576

#define SLUT_N ((NBINS+1)*256)        // 262400
#define N_INTS (3*NN+1+NE)            // 550001

#define FULL_AGG_FL   ((size_t)NN*256)
#define FULL_TOT_FL   (FULL_AGG_FL + WTOT + SLUT_N + N_INTS)
#define WS_FULL_BYTES (FULL_TOT_FL*4ull)
#define CH_AGG_FL     ((size_t)CNN*256)
#define CH_TOT_FL     (CH_AGG_FL + WTOT + SLUT_N + N_INTS)
#define WS_CH_BYTES   (CH_TOT_FL*4ull)

#define S160 0.07905694150420949f
#define S96  0.10206207261596576f

__device__ __forceinline__ float sigf(float x){
  return __builtin_amdgcn_rcpf(1.0f + __expf(-x));
}
__device__ __forceinline__ float siluf(float x){ return x * sigf(x); }

// ---- weights: transpose l1s,l1v; copy l2s,l2v ----
__global__ __launch_bounds__(256) void convert_weights(
    const float* __restrict__ l1s, const float* __restrict__ l1v,
    const float* __restrict__ l2s, const float* __restrict__ l2v,
    float* __restrict__ wgt)
{
  int i = blockIdx.x*256 + threadIdx.x;
  if (i < 12288){ int o=i>>6, m=i&63; wgt[RL1ST + i] = l1s[m*192+o]; return; }
  if (i < 16384){ int t=i-12288; int o=t>>6, m=t&63; wgt[RL1VT + t] = l1v[m*64+o]; return; }
  if (i < 21504){ int t=i-16384; wgt[RL2S + t] = l2s[t]; return; }
  if (i < 24576){ int t=i-21504; wgt[RL2V + t] = l2v[t]; return; }
}

// ---- SLUT[bin][256]: scal(x) at bin edges, component-remapped ----
__global__ __launch_bounds__(128) void build_lut(
    const float* __restrict__ w1, const float* __restrict__ b1,
    const float* __restrict__ w2, const float* __restrict__ b2,
    const float* __restrict__ w3, const float* __restrict__ b3,
    float* __restrict__ slut)
{
  __shared__ float h1[64], h2[64], scal[128];
  int bin = blockIdx.x;            // 0..NBINS
  float x = (float)bin / (float)NBINS;
  int t = threadIdx.x;
  if (t < 64) h1[t] = siluf(fmaf(x, w1[t], b1[t]));
  __syncthreads();
  if (t < 64){
    float a = b2[t];
    for (int k=0;k<64;k++) a = fmaf(h1[k], w2[k*64+t], a);
    h2[t] = siluf(a);
  }
  __syncthreads();
  {
    float a = b3[t];
    for (int k=0;k<64;k++) a = fmaf(h2[k], w3[k*128+t], a);
    scal[t] = a;
  }
  __syncthreads();
  for (int c=t; c<256; c+=128){
    int m=c>>3, q=c&7;
    int idx = (q==0)? m : (q==1)? (32+m) : (q<5)? (64+m) : (96+m);
    slut[(size_t)bin*256 + c] = scal[idx];
  }
}

// ================= CSR build =================
__global__ __launch_bounds__(256) void count_kernel(
    const int* __restrict__ rcv, int* __restrict__ cnt)
{
  int e = blockIdx.x*256 + threadIdx.x;
  if (e < NE) atomicAdd(&cnt[rcv[e]], 1);
}

__global__ __launch_bounds__(1024) void scan_kernel(
    const int* __restrict__ cnt, int* __restrict__ offs, int* __restrict__ curs)
{
  __shared__ int sdata[1024];
  int tid = threadIdx.x;
  const int CH = 49;
  int base = tid*CH;
  int s = 0;
  for (int i=0;i<CH;i++){ int idx=base+i; if (idx<NN) s += cnt[idx]; }
  sdata[tid] = s;
  __syncthreads();
  for (int off=1; off<1024; off<<=1){
    int t = 0;
    if (tid >= off) t = sdata[tid-off];
    __syncthreads();
    sdata[tid] += t;
    __syncthreads();
  }
  int run = sdata[tid] - s;
  for (int i=0;i<CH;i++){
    int idx = base+i;
    if (idx < NN){ offs[idx]=run; curs[idx]=run; run += cnt[idx]; }
  }
  if (tid == 1023) offs[NN] = run;
}

__global__ __launch_bounds__(256) void scatter_kernel(
    const int* __restrict__ rcv, int* __restrict__ curs, int* __restrict__ eids)
{
  int e = blockIdx.x*256 + threadIdx.x;
  if (e >= NE) return;
  int pos = atomicAdd(&curs[rcv[e]], 1);
  eids[pos] = e;
}

// ================= Edge+aggregate: wave per node, lane per 4 comps =========
__global__ __launch_bounds__(256) void edge_agg_kernel(
    const float* __restrict__ ns, const float* __restrict__ nv,
    const float* __restrict__ sh, const float* __restrict__ nrm,
    const int* __restrict__ snd,
    const int* __restrict__ offs, const int* __restrict__ eids,
    const float* __restrict__ slut,
    float* __restrict__ agg, int cn0, int cnn)
{
  int wave = threadIdx.x >> 6;
  int lane = threadIdx.x & 63;
  int nl = blockIdx.x*4 + wave;
  if (nl >= cnn) return;
  int n = cn0 + nl;
  int m = lane >> 1;
  int odd = lane & 1;
  int p0 = offs[n], p1 = offs[n+1];
  const float4* slut4 = (const float4*)slut;
  const float inv_sqrt3 = 0.57735026918962576f;
  float a0=0.f, a1=0.f, a2=0.f, a3=0.f;

  for (int p=p0; p<p1; p++){
    int e    = eids[p];
    int s    = snd[e];
    float x  = nrm[e];
    float4 y = *(const float4*)(sh + 4*e);
    float f = x * (float)NBINS;
    f = fminf(fmaxf(f, 0.0f), (float)NBINS - 0.001f);
    int bin = (int)f;
    float tt = f - (float)bin;
    float4 L0 = slut4[(size_t)bin*64 + lane];
    float4 L1 = slut4[(size_t)(bin+1)*64 + lane];
    float sc0 = fmaf(tt, L1.x-L0.x, L0.x);
    float sc1 = fmaf(tt, L1.y-L0.y, L0.y);
    float sc2 = fmaf(tt, L1.z-L0.z, L0.z);
    float sc3 = fmaf(tt, L1.w-L0.w, L0.w);

    float se = ns[(size_t)s*32 + m];
    const float* vp = nv + (size_t)s*96 + 3*m;
    float v0 = vp[0], v1 = vp[1], v2 = vp[2];

    float A0,A1,A2,A3;
    if (!odd){
      float dot = fmaf(y.w, v2, fmaf(y.z, v1, y.y*v0));
      A0 = y.x*se; A1 = dot*inv_sqrt3; A2 = y.x*v0; A3 = y.x*v1;
    } else {
      A0 = y.x*v2; A1 = y.y*se; A2 = y.z*se; A3 = y.w*se;
    }
    a0 = fmaf(A0, sc0, a0);
    a1 = fmaf(A1, sc1, a1);
    a2 = fmaf(A2, sc2, a2);
    a3 = fmaf(A3, sc3, a3);
  }
  int deg = p1 - p0;
  float inv = (deg > 0) ? __builtin_amdgcn_rcpf((float)deg) : 1.0f;
  float4 o; o.x=a0*inv; o.y=a1*inv; o.z=a2*inv; o.w=a3*inv;
  *(float4*)(agg + (size_t)nl*256 + 4*lane) = o;
}

// ================= Node phase v3: LDS-staged weights, split S/V ============
// Kernel S: scalar path. lane=node (64/block), 4 waves each do 32 act cols
// + their quarter of the ns@l2s rows into a private partial oacc[32];
// LDS tree-reduce into role 0, which writes out[:,0:32].
// LDS: l1sT[0:128] (32KB) + l2s (20KB) + red[64][33] (8.4KB) = 61.7KB
#define SW_L1  0
#define SW_L2  8192
#define SW_RED 13312
#define SW_TOT 15424

__global__ __launch_bounds__(256) __attribute__((amdgpu_waves_per_eu(2,2)))
void node_s_kernel(
    const float* __restrict__ ns, const float* __restrict__ wgt,
    const float* __restrict__ agg, int cn0, int cnn,
    float* __restrict__ out)
{
  __shared__ __align__(16) float sw[SW_TOT];
  int lane = threadIdx.x & 63, role = threadIdx.x >> 6;
  {
    const float4* s1 = (const float4*)(wgt + RL1ST);   // 8192 floats
    float4* d1 = (float4*)(sw + SW_L1);
    for (int i = threadIdx.x; i < 2048; i += 256) d1[i] = s1[i];
    const float4* s2 = (const float4*)(wgt + RL2S);    // 5120 floats
    float4* d2 = (float4*)(sw + SW_L2);
    for (int i = threadIdx.x; i < 1280; i += 256) d2[i] = s2[i];
  }
  __syncthreads();

  int nl = blockIdx.x*64 + lane;
  bool valid = (nl < cnn);
  int n = cn0 + nl;

  float aggs[64];
  float oacc[32];
  #pragma unroll
  for (int j=0;j<32;j++) oacc[j]=0.0f;

  if (valid){
    const float2* ar = (const float2*)(agg + (size_t)nl*256);
    #pragma unroll
    for (int g=0; g<32; g++){
      float2 v = ar[4*g];
      aggs[g] = v.x; aggs[32+g] = v.y;
    }
    const float4* colbase = (const float4*)(sw + SW_L1 + role*2048);
    for (int t=0;t<32;t++){
      const float4* col = colbase + t*16;
      float d0=0,d1=0,d2=0,d3=0;
      #pragma unroll
      for (int j=0;j<16;j++){
        float4 c = col[j];
        d0 = fmaf(aggs[4*j+0], c.x, d0);
        d1 = fmaf(aggs[4*j+1], c.y, d1);
        d2 = fmaf(aggs[4*j+2], c.z, d2);
        d3 = fmaf(aggs[4*j+3], c.w, d3);
      }
      float act = siluf(((d0+d1)+(d2+d3))*0.125f);
      const float4* row = (const float4*)(sw + SW_L2 + (role*32 + t)*32);
      #pragma unroll
      for (int j=0;j<8;j++){
        float4 w = row[j];
        oacc[4*j+0] = fmaf(act, w.x, oacc[4*j+0]);
        oacc[4*j+1] = fmaf(act, w.y, oacc[4*j+1]);
        oacc[4*j+2] = fmaf(act, w.z, oacc[4*j+2]);
        oacc[4*j+3] = fmaf(act, w.w, oacc[4*j+3]);
      }
    }
    // ns part: this role's 8 q rows (c_s rows 128+q)
    const float4* sp = (const float4*)(ns + (size_t)n*32 + role*8);
    #pragma unroll
    for (int q4=0;q4<2;q4++){
      float4 v = sp[q4];
      float vv[4] = {v.x, v.y, v.z, v.w};
      #pragma unroll
      for (int u=0;u<4;u++){
        int q = role*8 + q4*4 + u;
        const float4* row = (const float4*)(sw + SW_L2 + (128+q)*32);
        #pragma unroll
        for (int j=0;j<8;j++){
          float4 w = row[j];
          oacc[4*j+0] = fmaf(vv[u], w.x, oacc[4*j+0]);
          oacc[4*j+1] = fmaf(vv[u], w.y, oacc[4*j+1]);
          oacc[4*j+2] = fmaf(vv[u], w.z, oacc[4*j+2]);
          oacc[4*j+3] = fmaf(vv[u], w.w, oacc[4*j+3]);
        }
      }
    }
  }

  // reduce partials into role 0 (red padded to 33 floats/row: conflict-free)
  float* red = sw + SW_RED;
  for (int r=1;r<4;r++){
    __syncthreads();
    if (role==r && valid){
      #pragma unroll
      for (int j=0;j<32;j++) red[lane*33+j] = oacc[j];
    }
    __syncthreads();
    if (role==0 && valid){
      #pragma unroll
      for (int j=0;j<32;j++) oacc[j] += red[lane*33+j];
    }
  }

  if (role==0 && valid){
    float4* op = (float4*)(out + (size_t)n*128);
    #pragma unroll
    for (int j=0;j<8;j++){
      float4 o4;
      o4.x = oacc[4*j+0]*S160; o4.y = oacc[4*j+1]*S160;
      o4.z = oacc[4*j+2]*S160; o4.w = oacc[4*j+3]*S160;
      op[j] = o4;
    }
  }
}

// Kernel V: gates + vector path. lane=node (64/block), 3 waves.
// Phase A: wave r computes gate cols o==r (mod 3) -> sgate LDS.
// Phase B: wave k owns vector component k.
// LDS: gate cols l1sT[128:192] (16KB) + l1vT (16KB) + l2v (12KB) + sgate (16KB) = 60KB
#define VW_G   0
#define VW_V1  4096
#define VW_V2  8192
#define VW_SG  11264
#define VW_TOT 15360

__global__ __launch_bounds__(192) __attribute__((amdgpu_waves_per_eu(2,2)))
void node_v_kernel(
    const float* __restrict__ nv, const float* __restrict__ wgt,
    const float* __restrict__ agg, int cn0, int cnn,
    float* __restrict__ out)
{
  __shared__ __align__(16) float sw[VW_TOT];
  int lane = threadIdx.x & 63, role = threadIdx.x >> 6;  // role 0..2
  {
    // wgt floats [8192,16384) = gate cols + l1vT, contiguous
    const float4* s1 = (const float4*)(wgt + 8192);
    float4* d1 = (float4*)(sw + VW_G);
    for (int i = threadIdx.x; i < 2048; i += 192) d1[i] = s1[i];
    const float4* s2 = (const float4*)(wgt + RL2V);      // 3072 floats
    float4* d2 = (float4*)(sw + VW_V2);
    for (int i = threadIdx.x; i < 768; i += 192) d2[i] = s2[i];
  }
  __syncthreads();

  int nl = blockIdx.x*64 + lane;
  bool valid = (nl < cnn);
  int n = cn0 + nl;
  const float* arow = agg + (size_t)nl*256;

  if (valid){
    float aggs[64];
    const float2* ar = (const float2*)arow;
    #pragma unroll
    for (int g=0; g<32; g++){
      float2 v = ar[4*g];
      aggs[g] = v.x; aggs[32+g] = v.y;
    }
    for (int o=role; o<64; o+=3){
      const float4* col = (const float4*)(sw + VW_G + o*64);
      float d0=0,d1=0,d2=0,d3=0;
      #pragma unroll
      for (int j=0;j<16;j++){
        float4 c = col[j];
        d0 = fmaf(aggs[4*j+0], c.x, d0);
        d1 = fmaf(aggs[4*j+1], c.y, d1);
        d2 = fmaf(aggs[4*j+2], c.z, d2);
        d3 = fmaf(aggs[4*j+3], c.w, d3);
      }
      sw[VW_SG + o*64 + lane] = sigf(((d0+d1)+(d2+d3))*0.125f);
    }
  }
  __syncthreads();
  if (!valid) return;

  int k = role;
  float aggv[64], oacc[32];
  #pragma unroll
  for (int j=0;j<32;j++) oacc[j]=0.0f;
  #pragma unroll
  for (int g=0; g<32; g++){
    aggv[g]    = arow[8*g + 2 + k];
    aggv[32+g] = arow[8*g + 5 + k];
  }
  for (int o=0;o<64;o++){
    const float4* col = (const float4*)(sw + VW_V1 + o*64);
    float d0=0,d1=0,d2=0,d3=0;
    #pragma unroll
    for (int j=0;j<16;j++){
      float4 c = col[j];
      d0 = fmaf(aggv[4*j+0], c.x, d0);
      d1 = fmaf(aggv[4*j+1], c.y, d1);
      d2 = fmaf(aggv[4*j+2], c.z, d2);
      d3 = fmaf(aggv[4*j+3], c.w, d3);
    }
    float gv = (((d0+d1)+(d2+d3))*0.125f) * sw[VW_SG + o*64 + lane];
    const float4* row = (const float4*)(sw + VW_V2 + o*32);
    #pragma unroll
    for (int j=0;j<8;j++){
      float4 w = row[j];
      oacc[4*j+0] = fmaf(gv, w.x, oacc[4*j+0]);
      oacc[4*j+1] = fmaf(gv, w.y, oacc[4*j+1]);
      oacc[4*j+2] = fmaf(gv, w.z, oacc[4*j+2]);
      oacc[4*j+3] = fmaf(gv, w.w, oacc[4*j+3]);
    }
  }
  const float* vp = nv + (size_t)n*96 + k;
  #pragma unroll 8
  for (int q=0;q<32;q++){
    float a = vp[3*q];
    const float4* row = (const float4*)(sw + VW_V2 + (64+q)*32);
    #pragma unroll
    for (int j=0;j<8;j++){
      float4 w = row[j];
      oacc[4*j+0] = fmaf(a, w.x, oacc[4*j+0]);
      oacc[4*j+1] = fmaf(a, w.y, oacc[4*j+1]);
      oacc[4*j+2] = fmaf(a, w.z, oacc[4*j+2]);
      oacc[4*j+3] = fmaf(a, w.w, oacc[4*j+3]);
    }
  }
  float* op = out + (size_t)n*128 + 32 + k;
  #pragma unroll
  for (int j=0;j<32;j++) op[3*j] = oacc[j]*S96;
}

extern "C" void kernel_launch(void* const* d_in, const int* in_sizes, int n_in,
                              void* d_out, int out_size, void* d_ws, size_t ws_size,
                              hipStream_t stream) {
  const float* node_scalars = (const float*)d_in[0];
  const float* node_vectors = (const float*)d_in[1];
  const float* sh           = (const float*)d_in[2];
  const float* norm         = (const float*)d_in[3];
  const float* w1  = (const float*)d_in[4];
  const float* b1  = (const float*)d_in[5];
  const float* w2  = (const float*)d_in[6];
  const float* b2  = (const float*)d_in[7];
  const float* w3  = (const float*)d_in[8];
  const float* b3  = (const float*)d_in[9];
  const float* l1s = (const float*)d_in[10];
  const float* l1v = (const float*)d_in[11];
  const float* l2s = (const float*)d_in[12];
  const float* l2v = (const float*)d_in[13];
  const int* snd = (const int*)d_in[14];
  const int* rcv = (const int*)d_in[15];
  float* ws = (float*)d_ws;
  float* out = (float*)d_out;

  if (ws_size < WS_CH_BYTES) return;

  bool full = (ws_size >= WS_FULL_BYTES);
  size_t aggfl = full ? FULL_AGG_FL : CH_AGG_FL;
  float* agg  = ws;
  float* wgt  = ws + aggfl;
  float* slut = wgt + WTOT;
  int*   ib   = (int*)(slut + SLUT_N);
  int* cnt  = ib;
  int* offs = ib + NN;
  int* curs = ib + 2*NN + 1;
  int* eids = ib + 3*NN + 1;

  hipMemsetAsync(cnt, 0, NN*sizeof(int), stream);

  convert_weights<<<(WTOT+255)/256, 256, 0, stream>>>(l1s, l1v, l2s, l2v, wgt);
  build_lut<<<NBINS+1, 128, 0, stream>>>(w1,b1,w2,b2,w3,b3, slut);

  count_kernel<<<(NE+255)/256, 256, 0, stream>>>(rcv, cnt);
  scan_kernel<<<1, 1024, 0, stream>>>(cnt, offs, curs);
  scatter_kernel<<<(NE+255)/256, 256, 0, stream>>>(rcv, curs, eids);

  int nchunks = full ? 1 : 2;
  int csize   = full ? NN : CNN;
  for (int ch = 0; ch < nchunks; ch++){
    int cn0 = ch * csize;
    edge_agg_kernel<<<(csize+3)/4, 256, 0, stream>>>(
        node_scalars, node_vectors, sh, norm, snd, offs, eids, slut,
        agg, cn0, csize);
    node_s_kernel<<<(csize+63)/64, 256, 0, stream>>>(
        node_scalars, wgt, agg, cn0, csize, out);
    node_v_kernel<<<(csize+63)/64, 192, 0, stream>>>(
        node_vectors, wgt, agg, cn0, csize, out);
  }
}

// Round 2
// 486.616 us; speedup vs baseline: 1.1761x; 1.1761x over previous
//
#include <hip/hip_runtime.h>

#define NN 50000
#define NE 400000
#define CNN 25000
#define NBINS 1024

// weight offsets (layout from convert_weights)
#define RL1ST 0            // l1s transposed: (192,64), col-contiguous
#define RL1VT 12288        // l1v transposed: (64,64)
#define RL2S  16384        // l2s original (160,32)
#define RL2V  21504        // l2v original (96,32)
#define WTOT  24576

#define SLUT_N ((NBINS+1)*256)        // 262400
#define N_INTS (3*NN+1+NE)            // 550001

#define FULL_AGG_FL   ((size_t)NN*256)
#define FULL_TOT_FL   (FULL_AGG_FL + WTOT + SLUT_N + N_INTS)
#define WS_FULL_BYTES (FULL_TOT_FL*4ull)
#define CH_AGG_FL     ((size_t)CNN*256)
#define CH_TOT_FL     (CH_AGG_FL + WTOT + SLUT_N + N_INTS)
#define WS_CH_BYTES   (CH_TOT_FL*4ull)

#define S160 0.07905694150420949f
#define S96  0.10206207261596576f

__device__ __forceinline__ float sigf(float x){
  return __builtin_amdgcn_rcpf(1.0f + __expf(-x));
}
__device__ __forceinline__ float siluf(float x){ return x * sigf(x); }

// ---- weights: transpose l1s,l1v; copy l2s,l2v ----
__global__ __launch_bounds__(256) void convert_weights(
    const float* __restrict__ l1s, const float* __restrict__ l1v,
    const float* __restrict__ l2s, const float* __restrict__ l2v,
    float* __restrict__ wgt)
{
  int i = blockIdx.x*256 + threadIdx.x;
  if (i < 12288){ int o=i>>6, m=i&63; wgt[RL1ST + i] = l1s[m*192+o]; return; }
  if (i < 16384){ int t=i-12288; int o=t>>6, m=t&63; wgt[RL1VT + t] = l1v[m*64+o]; return; }
  if (i < 21504){ int t=i-16384; wgt[RL2S + t] = l2s[t]; return; }
  if (i < 24576){ int t=i-21504; wgt[RL2V + t] = l2v[t]; return; }
}

// ---- SLUT[bin][256]: scal(x) at bin edges, per-lane-slot order (c=m*8+q) ----
__global__ __launch_bounds__(128) void build_lut(
    const float* __restrict__ w1, const float* __restrict__ b1,
    const float* __restrict__ w2, const float* __restrict__ b2,
    const float* __restrict__ w3, const float* __restrict__ b3,
    float* __restrict__ slut)
{
  __shared__ float h1[64], h2[64], scal[128];
  int bin = blockIdx.x;            // 0..NBINS
  float x = (float)bin / (float)NBINS;
  int t = threadIdx.x;
  if (t < 64) h1[t] = siluf(fmaf(x, w1[t], b1[t]));
  __syncthreads();
  if (t < 64){
    float a = b2[t];
    for (int k=0;k<64;k++) a = fmaf(h1[k], w2[k*64+t], a);
    h2[t] = siluf(a);
  }
  __syncthreads();
  {
    float a = b3[t];
    for (int k=0;k<64;k++) a = fmaf(h2[k], w3[k*128+t], a);
    scal[t] = a;
  }
  __syncthreads();
  for (int c=t; c<256; c+=128){
    int m=c>>3, q=c&7;
    int idx = (q==0)? m : (q==1)? (32+m) : (q<5)? (64+m) : (96+m);
    slut[(size_t)bin*256 + c] = scal[idx];
  }
}

// ================= CSR build =================
__global__ __launch_bounds__(256) void count_kernel(
    const int* __restrict__ rcv, int* __restrict__ cnt)
{
  int e = blockIdx.x*256 + threadIdx.x;
  if (e < NE) atomicAdd(&cnt[rcv[e]], 1);
}

__global__ __launch_bounds__(1024) void scan_kernel(
    const int* __restrict__ cnt, int* __restrict__ offs, int* __restrict__ curs)
{
  __shared__ int sdata[1024];
  int tid = threadIdx.x;
  const int CH = 49;
  int base = tid*CH;
  int s = 0;
  for (int i=0;i<CH;i++){ int idx=base+i; if (idx<NN) s += cnt[idx]; }
  sdata[tid] = s;
  __syncthreads();
  for (int off=1; off<1024; off<<=1){
    int t = 0;
    if (tid >= off) t = sdata[tid-off];
    __syncthreads();
    sdata[tid] += t;
    __syncthreads();
  }
  int run = sdata[tid] - s;
  for (int i=0;i<CH;i++){
    int idx = base+i;
    if (idx < NN){ offs[idx]=run; curs[idx]=run; run += cnt[idx]; }
  }
  if (tid == 1023) offs[NN] = run;
}

__global__ __launch_bounds__(256) void scatter_kernel(
    const int* __restrict__ rcv, int* __restrict__ curs, int* __restrict__ eids)
{
  int e = blockIdx.x*256 + threadIdx.x;
  if (e >= NE) return;
  int pos = atomicAdd(&curs[rcv[e]], 1);
  eids[pos] = e;
}

// ================= Edge+aggregate: wave per node, lane per 4 comps =========
// Output layout (NEW): agg[node][c'] with c' = block*32 + m:
//   block0: y0*s (scal m)      block1: dot (scal 32+m)
//   block2: y0*v0   block3: y1_0*s   (aggv k=0)
//   block4: y0*v1   block5: y1_1*s   (aggv k=1)
//   block6: y0*v2   block7: y1_2*s   (aggv k=2)
// -> each node-phase consumer reads one contiguous 256B slice.
__global__ __launch_bounds__(256) void edge_agg_kernel(
    const float* __restrict__ ns, const float* __restrict__ nv,
    const float* __restrict__ sh, const float* __restrict__ nrm,
    const int* __restrict__ snd,
    const int* __restrict__ offs, const int* __restrict__ eids,
    const float* __restrict__ slut,
    float* __restrict__ agg, int cn0, int cnn)
{
  int wave = threadIdx.x >> 6;
  int lane = threadIdx.x & 63;
  int nl = blockIdx.x*4 + wave;
  if (nl >= cnn) return;
  int n = cn0 + nl;
  int m = lane >> 1;
  int odd = lane & 1;
  int p0 = offs[n], p1 = offs[n+1];
  const float4* slut4 = (const float4*)slut;
  const float inv_sqrt3 = 0.57735026918962576f;
  float a0=0.f, a1=0.f, a2=0.f, a3=0.f;

  for (int p=p0; p<p1; p++){
    int e    = eids[p];
    int s    = snd[e];
    float x  = nrm[e];
    float4 y = *(const float4*)(sh + 4*e);
    float f = x * (float)NBINS;
    f = fminf(fmaxf(f, 0.0f), (float)NBINS - 0.001f);
    int bin = (int)f;
    float tt = f - (float)bin;
    float4 L0 = slut4[(size_t)bin*64 + lane];
    float4 L1 = slut4[(size_t)(bin+1)*64 + lane];
    float sc0 = fmaf(tt, L1.x-L0.x, L0.x);
    float sc1 = fmaf(tt, L1.y-L0.y, L0.y);
    float sc2 = fmaf(tt, L1.z-L0.z, L0.z);
    float sc3 = fmaf(tt, L1.w-L0.w, L0.w);

    float se = ns[(size_t)s*32 + m];
    const float* vp = nv + (size_t)s*96 + 3*m;
    float v0 = vp[0], v1 = vp[1], v2 = vp[2];

    float A0,A1,A2,A3;
    if (!odd){
      float dot = fmaf(y.w, v2, fmaf(y.z, v1, y.y*v0));
      A0 = y.x*se; A1 = dot*inv_sqrt3; A2 = y.x*v0; A3 = y.x*v1;
    } else {
      A0 = y.x*v2; A1 = y.y*se; A2 = y.z*se; A3 = y.w*se;
    }
    a0 = fmaf(A0, sc0, a0);
    a1 = fmaf(A1, sc1, a1);
    a2 = fmaf(A2, sc2, a2);
    a3 = fmaf(A3, sc3, a3);
  }
  int deg = p1 - p0;
  float inv = (deg > 0) ? __builtin_amdgcn_rcpf((float)deg) : 1.0f;
  float* ap = agg + (size_t)nl*256;
  int pos0 = odd ? (192+m) : m;        // q4 : q0
  int pos1 = odd ? ( 96+m) : (32+m);   // q5 : q1
  int pos2 = odd ? (160+m) : (64+m);   // q6 : q2
  int pos3 = odd ? (224+m) : (128+m);  // q7 : q3
  ap[pos0] = a0*inv;
  ap[pos1] = a1*inv;
  ap[pos2] = a2*inv;
  ap[pos3] = a3*inv;
}

// ================= Node phase v4: no weight staging, contiguous agg slices =
// Weights read via wave-uniform (readfirstlane'd) global loads -> scalar/L1
// broadcast. LDS only for genuine cross-wave traffic.

// Kernel S: lane=node, 4 roles x (32 act cols + 8 ns rows) -> partial oacc,
// single-round LDS reduce (red[3][64][33] = 25.3KB), role0 writes out[:,0:32].
__global__ __launch_bounds__(256) __attribute__((amdgpu_waves_per_eu(3,8)))
void node_s_kernel(
    const float* __restrict__ ns, const float* __restrict__ wgt,
    const float* __restrict__ agg, int cn0, int cnn,
    float* __restrict__ out)
{
  __shared__ float red[3*64*33];     // 25.3 KB
  int lane = threadIdx.x & 63, role = threadIdx.x >> 6;
  int ro = __builtin_amdgcn_readfirstlane(role);
  int nl = blockIdx.x*64 + lane;
  bool valid = (nl < cnn);
  int nls = valid ? nl : (cnn-1);
  int n = cn0 + nl;

  float aggs[64];
  float oacc[32];
  #pragma unroll
  for (int j=0;j<32;j++) oacc[j]=0.0f;

  {
    const float4* ar = (const float4*)(agg + (size_t)nls*256);
    #pragma unroll
    for (int g=0; g<16; g++){
      float4 v = ar[g];
      aggs[4*g+0]=v.x; aggs[4*g+1]=v.y; aggs[4*g+2]=v.z; aggs[4*g+3]=v.w;
    }
  }
  // 32 act columns for this role
  const float* l1sT = wgt + RL1ST + ro*32*64;
  const float* l2s  = wgt + RL2S;
  for (int t=0;t<32;t++){
    const float4* col = (const float4*)(l1sT + t*64);
    float d0=0,d1=0,d2=0,d3=0;
    #pragma unroll
    for (int j=0;j<16;j++){
      float4 c = col[j];
      d0 = fmaf(aggs[4*j+0], c.x, d0);
      d1 = fmaf(aggs[4*j+1], c.y, d1);
      d2 = fmaf(aggs[4*j+2], c.z, d2);
      d3 = fmaf(aggs[4*j+3], c.w, d3);
    }
    float act = siluf(((d0+d1)+(d2+d3))*0.125f);
    const float4* row = (const float4*)(l2s + (size_t)(ro*32 + t)*32);
    #pragma unroll
    for (int j=0;j<8;j++){
      float4 w = row[j];
      oacc[4*j+0] = fmaf(act, w.x, oacc[4*j+0]);
      oacc[4*j+1] = fmaf(act, w.y, oacc[4*j+1]);
      oacc[4*j+2] = fmaf(act, w.z, oacc[4*j+2]);
      oacc[4*j+3] = fmaf(act, w.w, oacc[4*j+3]);
    }
  }
  // ns part: this role's 8 q rows (c_s rows 128+q)
  {
    const float4* sp = (const float4*)(ns + (size_t)(cn0+nls)*32 + ro*8);
    #pragma unroll
    for (int q4=0;q4<2;q4++){
      float4 v = sp[q4];
      float vv[4] = {v.x, v.y, v.z, v.w};
      #pragma unroll
      for (int u=0;u<4;u++){
        int q = ro*8 + q4*4 + u;
        const float4* row = (const float4*)(l2s + (size_t)(128+q)*32);
        #pragma unroll
        for (int j=0;j<8;j++){
          float4 w = row[j];
          oacc[4*j+0] = fmaf(vv[u], w.x, oacc[4*j+0]);
          oacc[4*j+1] = fmaf(vv[u], w.y, oacc[4*j+1]);
          oacc[4*j+2] = fmaf(vv[u], w.z, oacc[4*j+2]);
          oacc[4*j+3] = fmaf(vv[u], w.w, oacc[4*j+3]);
        }
      }
    }
  }

  // single-round reduce into role 0
  if (role != 0){
    float* rp = red + (role-1)*(64*33) + lane*33;
    #pragma unroll
    for (int j=0;j<32;j++) rp[j] = oacc[j];
  }
  __syncthreads();
  if (role == 0 && valid){
    #pragma unroll
    for (int j=0;j<32;j++)
      oacc[j] += red[0*(64*33)+lane*33+j] + red[1*(64*33)+lane*33+j]
               + red[2*(64*33)+lane*33+j];
    float4* op = (float4*)(out + (size_t)n*128);
    #pragma unroll
    for (int j=0;j<8;j++){
      float4 o4;
      o4.x = oacc[4*j+0]*S160; o4.y = oacc[4*j+1]*S160;
      o4.z = oacc[4*j+2]*S160; o4.w = oacc[4*j+3]*S160;
      op[j] = o4;
    }
  }
}

// Kernel V: lane=node, 3 waves. Phase A: wave r computes gate cols o==r(mod3)
// -> sgate LDS. Phase B: wave k owns vector component k. Output staged in LDS
// (rows padded to 97 floats) and written back coalesced as float4.
// LDS: union{ sgate 16KB ; sout 64x97 } = 24.8KB
__global__ __launch_bounds__(192) __attribute__((amdgpu_waves_per_eu(3,8)))
void node_v_kernel(
    const float* __restrict__ nv, const float* __restrict__ wgt,
    const float* __restrict__ agg, int cn0, int cnn,
    float* __restrict__ out)
{
  __shared__ float sw[64*97];        // 24.8 KB (sgate uses first 4096 floats)
  int lane = threadIdx.x & 63, role = threadIdx.x >> 6;  // role 0..2
  int ro = __builtin_amdgcn_readfirstlane(role);
  int nl = blockIdx.x*64 + lane;
  bool valid = (nl < cnn);
  int nls = valid ? nl : (cnn-1);
  int n = cn0 + nl;
  const float* arow = agg + (size_t)nls*256;

  // ---- Phase A: gates ----
  {
    float aggs[64];
    const float4* ar = (const float4*)arow;
    #pragma unroll
    for (int g=0; g<16; g++){
      float4 v = ar[g];
      aggs[4*g+0]=v.x; aggs[4*g+1]=v.y; aggs[4*g+2]=v.z; aggs[4*g+3]=v.w;
    }
    const float* l1g = wgt + RL1ST + 128*64;     // gate cols 128..191
    for (int o=ro; o<64; o+=3){
      const float4* col = (const float4*)(l1g + o*64);
      float d0=0,d1=0,d2=0,d3=0;
      #pragma unroll
      for (int j=0;j<16;j++){
        float4 c = col[j];
        d0 = fmaf(aggs[4*j+0], c.x, d0);
        d1 = fmaf(aggs[4*j+1], c.y, d1);
        d2 = fmaf(aggs[4*j+2], c.z, d2);
        d3 = fmaf(aggs[4*j+3], c.w, d3);
      }
      sw[o*64+lane] = sigf(((d0+d1)+(d2+d3))*0.125f);
    }
  }
  __syncthreads();

  // ---- Phase B: component k = role ----
  int k = role;
  float aggv[64], oacc[32];
  #pragma unroll
  for (int j=0;j<32;j++) oacc[j]=0.0f;
  {
    const float4* av = (const float4*)(arow + 64 + 64*k);
    #pragma unroll
    for (int g=0; g<16; g++){
      float4 v = av[g];
      aggv[4*g+0]=v.x; aggv[4*g+1]=v.y; aggv[4*g+2]=v.z; aggv[4*g+3]=v.w;
    }
  }
  const float* l1vT = wgt + RL1VT;
  const float* l2v  = wgt + RL2V;
  for (int o=0;o<64;o++){
    const float4* col = (const float4*)(l1vT + o*64);
    float d0=0,d1=0,d2=0,d3=0;
    #pragma unroll
    for (int j=0;j<16;j++){
      float4 c = col[j];
      d0 = fmaf(aggv[4*j+0], c.x, d0);
      d1 = fmaf(aggv[4*j+1], c.y, d1);
      d2 = fmaf(aggv[4*j+2], c.z, d2);
      d3 = fmaf(aggv[4*j+3], c.w, d3);
    }
    float gv = (((d0+d1)+(d2+d3))*0.125f) * sw[o*64+lane];
    const float4* row = (const float4*)(l2v + (size_t)o*32);
    #pragma unroll
    for (int j=0;j<8;j++){
      float4 w = row[j];
      oacc[4*j+0] = fmaf(gv, w.x, oacc[4*j+0]);
      oacc[4*j+1] = fmaf(gv, w.y, oacc[4*j+1]);
      oacc[4*j+2] = fmaf(gv, w.z, oacc[4*j+2]);
      oacc[4*j+3] = fmaf(gv, w.w, oacc[4*j+3]);
    }
  }
  {
    const float* vp = nv + (size_t)(cn0+nls)*96 + k;
    #pragma unroll 8
    for (int q=0;q<32;q++){
      float a = vp[3*q];
      const float4* row = (const float4*)(l2v + (size_t)(64+q)*32);
      #pragma unroll
      for (int j=0;j<8;j++){
        float4 w = row[j];
        oacc[4*j+0] = fmaf(a, w.x, oacc[4*j+0]);
        oacc[4*j+1] = fmaf(a, w.y, oacc[4*j+1]);
        oacc[4*j+2] = fmaf(a, w.z, oacc[4*j+2]);
        oacc[4*j+3] = fmaf(a, w.w, oacc[4*j+3]);
      }
    }
  }

  // ---- stage outputs in LDS (rows padded to 97), then coalesced write ----
  __syncthreads();          // done reading sgate region
  if (valid){
    #pragma unroll
    for (int j=0;j<32;j++) sw[lane*97 + 3*j + k] = oacc[j]*S96;
  }
  __syncthreads();
  int nb = blockIdx.x*64;
  #pragma unroll
  for (int r=0;r<8;r++){
    int F = r*192 + threadIdx.x;       // 0..1535 -> 64 nodes x 24 float4
    int i = F/24, j = F%24;
    if (nb + i < cnn){
      float4 o4;
      o4.x = sw[i*97 + 4*j + 0];
      o4.y = sw[i*97 + 4*j + 1];
      o4.z = sw[i*97 + 4*j + 2];
      o4.w = sw[i*97 + 4*j + 3];
      *(float4*)(out + (size_t)(cn0+nb+i)*128 + 32 + 4*j) = o4;
    }
  }
}

extern "C" void kernel_launch(void* const* d_in, const int* in_sizes, int n_in,
                              void* d_out, int out_size, void* d_ws, size_t ws_size,
                              hipStream_t stream) {
  const float* node_scalars = (const float*)d_in[0];
  const float* node_vectors = (const float*)d_in[1];
  const float* sh           = (const float*)d_in[2];
  const float* norm         = (const float*)d_in[3];
  const float* w1  = (const float*)d_in[4];
  const float* b1  = (const float*)d_in[5];
  const float* w2  = (const float*)d_in[6];
  const float* b2  = (const float*)d_in[7];
  const float* w3  = (const float*)d_in[8];
  const float* b3  = (const float*)d_in[9];
  const float* l1s = (const float*)d_in[10];
  const float* l1v = (const float*)d_in[11];
  const float* l2s = (const float*)d_in[12];
  const float* l2v = (const float*)d_in[13];
  const int* snd = (const int*)d_in[14];
  const int* rcv = (const int*)d_in[15];
  float* ws = (float*)d_ws;
  float* out = (float*)d_out;

  if (ws_size < WS_CH_BYTES) return;

  bool full = (ws_size >= WS_FULL_BYTES);
  size_t aggfl = full ? FULL_AGG_FL : CH_AGG_FL;
  float* agg  = ws;
  float* wgt  = ws + aggfl;
  float* slut = wgt + WTOT;
  int*   ib   = (int*)(slut + SLUT_N);
  int* cnt  = ib;
  int* offs = ib + NN;
  int* curs = ib + 2*NN + 1;
  int* eids = ib + 3*NN + 1;

  hipMemsetAsync(cnt, 0, NN*sizeof(int), stream);

  convert_weights<<<(WTOT+255)/256, 256, 0, stream>>>(l1s, l1v, l2s, l2v, wgt);
  build_lut<<<NBINS+1, 128, 0, stream>>>(w1,b1,w2,b2,w3,b3, slut);

  count_kernel<<<(NE+255)/256, 256, 0, stream>>>(rcv, cnt);
  scan_kernel<<<1, 1024, 0, stream>>>(cnt, offs, curs);
  scatter_kernel<<<(NE+255)/256, 256, 0, stream>>>(rcv, curs, eids);

  int nchunks = full ? 1 : 2;
  int csize   = full ? NN : CNN;
  for (int ch = 0; ch < nchunks; ch++){
    int cn0 = ch * csize;
    edge_agg_kernel<<<(csize+3)/4, 256, 0, stream>>>(
        node_scalars, node_vectors, sh, norm, snd, offs, eids, slut,
        agg, cn0, csize);
    node_s_kernel<<<(csize+63)/64, 256, 0, stream>>>(
        node_scalars, wgt, agg, cn0, csize, out);
    node_v_kernel<<<(csize+63)/64, 192, 0, stream>>>(
        node_vectors, wgt, agg, cn0, csize, out);
  }
}

// Round 3
// 355.176 us; speedup vs baseline: 1.6113x; 1.3701x over previous
//
#include <hip/hip_runtime.h>

#define NN 50000
#define NE 400000
#define CNN 25000
#define NBINS 1024

// weight offsets (layout from convert_weights)
#define RL1ST 0            // l1s transposed: (192,64), col-contiguous
#define RL1VT 12288        // l1v transposed: (64,64)
#define RL2S  16384        // l2s original (160,32)
#define RL2V  21504        // l2v original (96,32)
#define WTOT  24576

#define SLUT_N ((NBINS+1)*256)        // 262400
#define N_INTS (3*NN+1+NE+512)        // + bsum/bbase

#define FULL_AGG_FL   ((size_t)NN*256)
#define FULL_TOT_FL   (FULL_AGG_FL + WTOT + SLUT_N + N_INTS)
#define WS_FULL_BYTES (FULL_TOT_FL*4ull)
#define CH_AGG_FL     ((size_t)CNN*256)
#define CH_TOT_FL     (CH_AGG_FL + WTOT + SLUT_N + N_INTS)
#define WS_CH_BYTES   (CH_TOT_FL*4ull)

#define SCAN_B 196                    // ceil(NN/256)

#define S160 0.07905694150420949f
#define S96  0.10206207261596576f

__device__ __forceinline__ float sigf(float x){
  return __builtin_amdgcn_rcpf(1.0f + __expf(-x));
}
__device__ __forceinline__ float siluf(float x){ return x * sigf(x); }

// ---- weights: transpose l1s,l1v; copy l2s,l2v ----
__global__ __launch_bounds__(256) void convert_weights(
    const float* __restrict__ l1s, const float* __restrict__ l1v,
    const float* __restrict__ l2s, const float* __restrict__ l2v,
    float* __restrict__ wgt)
{
  int i = blockIdx.x*256 + threadIdx.x;
  if (i < 12288){ int o=i>>6, m=i&63; wgt[RL1ST + i] = l1s[m*192+o]; return; }
  if (i < 16384){ int t=i-12288; int o=t>>6, m=t&63; wgt[RL1VT + t] = l1v[m*64+o]; return; }
  if (i < 21504){ int t=i-16384; wgt[RL2S + t] = l2s[t]; return; }
  if (i < 24576){ int t=i-21504; wgt[RL2V + t] = l2v[t]; return; }
}

// ---- SLUT[bin][256]: scal(x) at bin edges, per-lane-slot order (c=m*8+q) ----
__global__ __launch_bounds__(128) void build_lut(
    const float* __restrict__ w1, const float* __restrict__ b1,
    const float* __restrict__ w2, const float* __restrict__ b2,
    const float* __restrict__ w3, const float* __restrict__ b3,
    float* __restrict__ slut)
{
  __shared__ float h1[64], h2[64], scal[128];
  int bin = blockIdx.x;            // 0..NBINS
  float x = (float)bin / (float)NBINS;
  int t = threadIdx.x;
  if (t < 64) h1[t] = siluf(fmaf(x, w1[t], b1[t]));
  __syncthreads();
  if (t < 64){
    float a = b2[t];
    for (int k=0;k<64;k++) a = fmaf(h1[k], w2[k*64+t], a);
    h2[t] = siluf(a);
  }
  __syncthreads();
  {
    float a = b3[t];
    for (int k=0;k<64;k++) a = fmaf(h2[k], w3[k*128+t], a);
    scal[t] = a;
  }
  __syncthreads();
  for (int c=t; c<256; c+=128){
    int m=c>>3, q=c&7;
    int idx = (q==0)? m : (q==1)? (32+m) : (q<5)? (64+m) : (96+m);
    slut[(size_t)bin*256 + c] = scal[idx];
  }
}

// ================= CSR build =================
__global__ __launch_bounds__(256) void count_kernel(
    const int* __restrict__ rcv, int* __restrict__ cnt)
{
  int e = blockIdx.x*256 + threadIdx.x;
  if (e < NE) atomicAdd(&cnt[rcv[e]], 1);
}

// multi-block scan, stage A: block-local exclusive scan + block sums
__global__ __launch_bounds__(256) void scan_a(
    const int* __restrict__ cnt, int* __restrict__ offs, int* __restrict__ bsum)
{
  __shared__ int sd[256];
  int tid = threadIdx.x;
  int i = blockIdx.x*256 + tid;
  int c = (i < NN) ? cnt[i] : 0;
  sd[tid] = c;
  __syncthreads();
  for (int off=1; off<256; off<<=1){
    int t = (tid >= off) ? sd[tid-off] : 0;
    __syncthreads();
    sd[tid] += t;
    __syncthreads();
  }
  if (i < NN) offs[i] = sd[tid] - c;          // local exclusive
  if (tid == 255) bsum[blockIdx.x] = sd[255]; // block total
}

// stage B: scan of block sums (196 values), also writes offs[NN]=total
__global__ __launch_bounds__(256) void scan_b(
    const int* __restrict__ bsum, int* __restrict__ bbase, int* __restrict__ offs)
{
  __shared__ int sd[256];
  int tid = threadIdx.x;
  int v = (tid < SCAN_B) ? bsum[tid] : 0;
  sd[tid] = v;
  __syncthreads();
  for (int off=1; off<256; off<<=1){
    int t = (tid >= off) ? sd[tid-off] : 0;
    __syncthreads();
    sd[tid] += t;
    __syncthreads();
  }
  if (tid < SCAN_B) bbase[tid] = sd[tid] - v;
  if (tid == 255) offs[NN] = sd[255];
}

// stage C: add block base, init cursors
__global__ __launch_bounds__(256) void scan_c(
    const int* __restrict__ bbase, int* __restrict__ offs, int* __restrict__ curs)
{
  int i = blockIdx.x*256 + threadIdx.x;
  if (i < NN){
    int o = offs[i] + bbase[blockIdx.x];
    offs[i] = o;
    curs[i] = o;
  }
}

__global__ __launch_bounds__(256) void scatter_kernel(
    const int* __restrict__ rcv, int* __restrict__ curs, int* __restrict__ eids)
{
  int e = blockIdx.x*256 + threadIdx.x;
  if (e >= NE) return;
  int pos = atomicAdd(&curs[rcv[e]], 1);
  eids[pos] = e;
}

// ================= Edge+aggregate: wave per node, lane per 4 comps =========
// Output layout: agg[node][c'] with c' = block*32 + m:
//   block0: y0*s (scal m)      block1: dot (scal 32+m)
//   block2: y0*v0   block3: y1_0*s   (aggv k=0)
//   block4: y0*v1   block5: y1_1*s   (aggv k=1)
//   block6: y0*v2   block7: y1_2*s   (aggv k=2)
// One-edge-ahead software prefetch of the meta chain (e -> s, nrm, sh).
__global__ __launch_bounds__(256) void edge_agg_kernel(
    const float* __restrict__ ns, const float* __restrict__ nv,
    const float* __restrict__ sh, const float* __restrict__ nrm,
    const int* __restrict__ snd,
    const int* __restrict__ offs, const int* __restrict__ eids,
    const float* __restrict__ slut,
    float* __restrict__ agg, int cn0, int cnn)
{
  int wave = threadIdx.x >> 6;
  int lane = threadIdx.x & 63;
  int nl = blockIdx.x*4 + wave;
  if (nl >= cnn) return;
  int n = cn0 + nl;
  int m = lane >> 1;
  int odd = lane & 1;
  int p0 = offs[n], p1 = offs[n+1];
  const float4* slut4 = (const float4*)slut;
  const float inv_sqrt3 = 0.57735026918962576f;
  float a0=0.f, a1=0.f, a2=0.f, a3=0.f;

  if (p0 < p1){
    int e = eids[p0];
    int s = snd[e];
    float x = nrm[e];
    float4 y = *(const float4*)(sh + 4*e);
    for (int p=p0; p<p1; p++){
      // prefetch next edge's meta chain (clamped, branchless)
      int pn = (p+1 < p1) ? (p+1) : p;
      int en = eids[pn];
      int sn = snd[en];
      float xn = nrm[en];
      float4 yn = *(const float4*)(sh + 4*en);

      float f = x * (float)NBINS;
      f = fminf(fmaxf(f, 0.0f), (float)NBINS - 0.001f);
      int bin = (int)f;
      float tt = f - (float)bin;
      float4 L0 = slut4[(size_t)bin*64 + lane];
      float4 L1 = slut4[(size_t)(bin+1)*64 + lane];
      float sc0 = fmaf(tt, L1.x-L0.x, L0.x);
      float sc1 = fmaf(tt, L1.y-L0.y, L0.y);
      float sc2 = fmaf(tt, L1.z-L0.z, L0.z);
      float sc3 = fmaf(tt, L1.w-L0.w, L0.w);

      float se = ns[(size_t)s*32 + m];
      const float* vp = nv + (size_t)s*96 + 3*m;
      float v0 = vp[0], v1 = vp[1], v2 = vp[2];

      float A0,A1,A2,A3;
      if (!odd){
        float dot = fmaf(y.w, v2, fmaf(y.z, v1, y.y*v0));
        A0 = y.x*se; A1 = dot*inv_sqrt3; A2 = y.x*v0; A3 = y.x*v1;
      } else {
        A0 = y.x*v2; A1 = y.y*se; A2 = y.z*se; A3 = y.w*se;
      }
      a0 = fmaf(A0, sc0, a0);
      a1 = fmaf(A1, sc1, a1);
      a2 = fmaf(A2, sc2, a2);
      a3 = fmaf(A3, sc3, a3);

      e = en; s = sn; x = xn; y = yn;
    }
  }
  int deg = p1 - p0;
  float inv = (deg > 0) ? __builtin_amdgcn_rcpf((float)deg) : 1.0f;
  float* ap = agg + (size_t)nl*256;
  int pos0 = odd ? (192+m) : m;        // q4 : q0
  int pos1 = odd ? ( 96+m) : (32+m);   // q5 : q1
  int pos2 = odd ? (160+m) : (64+m);   // q6 : q2
  int pos3 = odd ? (224+m) : (128+m);  // q7 : q3
  ap[pos0] = a0*inv;
  ap[pos1] = a1*inv;
  ap[pos2] = a2*inv;
  ap[pos3] = a3*inv;
}

// ================= Node phase: no weight staging, contiguous agg slices ====
// Kernel S: lane=node, 4 roles x (32 act cols + 8 ns rows) -> partial oacc,
// single-round LDS reduce, role0 writes out[:,0:32].
__global__ __launch_bounds__(256) __attribute__((amdgpu_waves_per_eu(3,8)))
void node_s_kernel(
    const float* __restrict__ ns, const float* __restrict__ wgt,
    const float* __restrict__ agg, int cn0, int cnn,
    float* __restrict__ out)
{
  __shared__ float red[3*64*33];     // 25.3 KB
  int lane = threadIdx.x & 63, role = threadIdx.x >> 6;
  int ro = __builtin_amdgcn_readfirstlane(role);
  int nl = blockIdx.x*64 + lane;
  bool valid = (nl < cnn);
  int nls = valid ? nl : (cnn-1);
  int n = cn0 + nl;

  float aggs[64];
  float oacc[32];
  #pragma unroll
  for (int j=0;j<32;j++) oacc[j]=0.0f;

  {
    const float4* ar = (const float4*)(agg + (size_t)nls*256);
    #pragma unroll
    for (int g=0; g<16; g++){
      float4 v = ar[g];
      aggs[4*g+0]=v.x; aggs[4*g+1]=v.y; aggs[4*g+2]=v.z; aggs[4*g+3]=v.w;
    }
  }
  // 32 act columns for this role
  const float* l1sT = wgt + RL1ST + ro*32*64;
  const float* l2s  = wgt + RL2S;
  for (int t=0;t<32;t++){
    const float4* col = (const float4*)(l1sT + t*64);
    float d0=0,d1=0,d2=0,d3=0;
    #pragma unroll
    for (int j=0;j<16;j++){
      float4 c = col[j];
      d0 = fmaf(aggs[4*j+0], c.x, d0);
      d1 = fmaf(aggs[4*j+1], c.y, d1);
      d2 = fmaf(aggs[4*j+2], c.z, d2);
      d3 = fmaf(aggs[4*j+3], c.w, d3);
    }
    float act = siluf(((d0+d1)+(d2+d3))*0.125f);
    const float4* row = (const float4*)(l2s + (size_t)(ro*32 + t)*32);
    #pragma unroll
    for (int j=0;j<8;j++){
      float4 w = row[j];
      oacc[4*j+0] = fmaf(act, w.x, oacc[4*j+0]);
      oacc[4*j+1] = fmaf(act, w.y, oacc[4*j+1]);
      oacc[4*j+2] = fmaf(act, w.z, oacc[4*j+2]);
      oacc[4*j+3] = fmaf(act, w.w, oacc[4*j+3]);
    }
  }
  // ns part: this role's 8 q rows (c_s rows 128+q)
  {
    const float4* sp = (const float4*)(ns + (size_t)(cn0+nls)*32 + ro*8);
    #pragma unroll
    for (int q4=0;q4<2;q4++){
      float4 v = sp[q4];
      float vv[4] = {v.x, v.y, v.z, v.w};
      #pragma unroll
      for (int u=0;u<4;u++){
        int q = ro*8 + q4*4 + u;
        const float4* row = (const float4*)(l2s + (size_t)(128+q)*32);
        #pragma unroll
        for (int j=0;j<8;j++){
          float4 w = row[j];
          oacc[4*j+0] = fmaf(vv[u], w.x, oacc[4*j+0]);
          oacc[4*j+1] = fmaf(vv[u], w.y, oacc[4*j+1]);
          oacc[4*j+2] = fmaf(vv[u], w.z, oacc[4*j+2]);
          oacc[4*j+3] = fmaf(vv[u], w.w, oacc[4*j+3]);
        }
      }
    }
  }

  // single-round reduce into role 0
  if (role != 0){
    float* rp = red + (role-1)*(64*33) + lane*33;
    #pragma unroll
    for (int j=0;j<32;j++) rp[j] = oacc[j];
  }
  __syncthreads();
  if (role == 0 && valid){
    #pragma unroll
    for (int j=0;j<32;j++)
      oacc[j] += red[0*(64*33)+lane*33+j] + red[1*(64*33)+lane*33+j]
               + red[2*(64*33)+lane*33+j];
    float4* op = (float4*)(out + (size_t)n*128);
    #pragma unroll
    for (int j=0;j<8;j++){
      float4 o4;
      o4.x = oacc[4*j+0]*S160; o4.y = oacc[4*j+1]*S160;
      o4.z = oacc[4*j+2]*S160; o4.w = oacc[4*j+3]*S160;
      op[j] = o4;
    }
  }
}

// Kernel V: lane=node, 3 waves. Phase A: gates -> LDS. Phase B: wave k owns
// vector component k. Output staged in LDS (rows padded to 97), coalesced write.
__global__ __launch_bounds__(192) __attribute__((amdgpu_waves_per_eu(3,8)))
void node_v_kernel(
    const float* __restrict__ nv, const float* __restrict__ wgt,
    const float* __restrict__ agg, int cn0, int cnn,
    float* __restrict__ out)
{
  __shared__ float sw[64*97];        // 24.8 KB (sgate uses first 4096 floats)
  int lane = threadIdx.x & 63, role = threadIdx.x >> 6;  // role 0..2
  int ro = __builtin_amdgcn_readfirstlane(role);
  int nl = blockIdx.x*64 + lane;
  bool valid = (nl < cnn);
  int nls = valid ? nl : (cnn-1);
  const float* arow = agg + (size_t)nls*256;

  // ---- Phase A: gates ----
  {
    float aggs[64];
    const float4* ar = (const float4*)arow;
    #pragma unroll
    for (int g=0; g<16; g++){
      float4 v = ar[g];
      aggs[4*g+0]=v.x; aggs[4*g+1]=v.y; aggs[4*g+2]=v.z; aggs[4*g+3]=v.w;
    }
    const float* l1g = wgt + RL1ST + 128*64;     // gate cols 128..191
    for (int o=ro; o<64; o+=3){
      const float4* col = (const float4*)(l1g + o*64);
      float d0=0,d1=0,d2=0,d3=0;
      #pragma unroll
      for (int j=0;j<16;j++){
        float4 c = col[j];
        d0 = fmaf(aggs[4*j+0], c.x, d0);
        d1 = fmaf(aggs[4*j+1], c.y, d1);
        d2 = fmaf(aggs[4*j+2], c.z, d2);
        d3 = fmaf(aggs[4*j+3], c.w, d3);
      }
      sw[o*64+lane] = sigf(((d0+d1)+(d2+d3))*0.125f);
    }
  }
  __syncthreads();

  // ---- Phase B: component k = role ----
  int k = role;
  float aggv[64], oacc[32];
  #pragma unroll
  for (int j=0;j<32;j++) oacc[j]=0.0f;
  {
    const float4* av = (const float4*)(arow + 64 + 64*k);
    #pragma unroll
    for (int g=0; g<16; g++){
      float4 v = av[g];
      aggv[4*g+0]=v.x; aggv[4*g+1]=v.y; aggv[4*g+2]=v.z; aggv[4*g+3]=v.w;
    }
  }
  const float* l1vT = wgt + RL1VT;
  const float* l2v  = wgt + RL2V;
  for (int o=0;o<64;o++){
    const float4* col = (const float4*)(l1vT + o*64);
    float d0=0,d1=0,d2=0,d3=0;
    #pragma unroll
    for (int j=0;j<16;j++){
      float4 c = col[j];
      d0 = fmaf(aggv[4*j+0], c.x, d0);
      d1 = fmaf(aggv[4*j+1], c.y, d1);
      d2 = fmaf(aggv[4*j+2], c.z, d2);
      d3 = fmaf(aggv[4*j+3], c.w, d3);
    }
    float gv = (((d0+d1)+(d2+d3))*0.125f) * sw[o*64+lane];
    const float4* row = (const float4*)(l2v + (size_t)o*32);
    #pragma unroll
    for (int j=0;j<8;j++){
      float4 w = row[j];
      oacc[4*j+0] = fmaf(gv, w.x, oacc[4*j+0]);
      oacc[4*j+1] = fmaf(gv, w.y, oacc[4*j+1]);
      oacc[4*j+2] = fmaf(gv, w.z, oacc[4*j+2]);
      oacc[4*j+3] = fmaf(gv, w.w, oacc[4*j+3]);
    }
  }
  {
    const float* vp = nv + (size_t)(cn0+nls)*96 + k;
    #pragma unroll 8
    for (int q=0;q<32;q++){
      float a = vp[3*q];
      const float4* row = (const float4*)(l2v + (size_t)(64+q)*32);
      #pragma unroll
      for (int j=0;j<8;j++){
        float4 w = row[j];
        oacc[4*j+0] = fmaf(a, w.x, oacc[4*j+0]);
        oacc[4*j+1] = fmaf(a, w.y, oacc[4*j+1]);
        oacc[4*j+2] = fmaf(a, w.z, oacc[4*j+2]);
        oacc[4*j+3] = fmaf(a, w.w, oacc[4*j+3]);
      }
    }
  }

  // ---- stage outputs in LDS (rows padded to 97), then coalesced write ----
  __syncthreads();          // done reading sgate region
  if (valid){
    #pragma unroll
    for (int j=0;j<32;j++) sw[lane*97 + 3*j + k] = oacc[j]*S96;
  }
  __syncthreads();
  int nb = blockIdx.x*64;
  #pragma unroll
  for (int r=0;r<8;r++){
    int F = r*192 + threadIdx.x;       // 0..1535 -> 64 nodes x 24 float4
    int i = F/24, j = F%24;
    if (nb + i < cnn){
      float4 o4;
      o4.x = sw[i*97 + 4*j + 0];
      o4.y = sw[i*97 + 4*j + 1];
      o4.z = sw[i*97 + 4*j + 2];
      o4.w = sw[i*97 + 4*j + 3];
      *(float4*)(out + (size_t)(cn0+nb+i)*128 + 32 + 4*j) = o4;
    }
  }
}

extern "C" void kernel_launch(void* const* d_in, const int* in_sizes, int n_in,
                              void* d_out, int out_size, void* d_ws, size_t ws_size,
                              hipStream_t stream) {
  const float* node_scalars = (const float*)d_in[0];
  const float* node_vectors = (const float*)d_in[1];
  const float* sh           = (const float*)d_in[2];
  const float* norm         = (const float*)d_in[3];
  const float* w1  = (const float*)d_in[4];
  const float* b1  = (const float*)d_in[5];
  const float* w2  = (const float*)d_in[6];
  const float* b2  = (const float*)d_in[7];
  const float* w3  = (const float*)d_in[8];
  const float* b3  = (const float*)d_in[9];
  const float* l1s = (const float*)d_in[10];
  const float* l1v = (const float*)d_in[11];
  const float* l2s = (const float*)d_in[12];
  const float* l2v = (const float*)d_in[13];
  const int* snd = (const int*)d_in[14];
  const int* rcv = (const int*)d_in[15];
  float* ws = (float*)d_ws;
  float* out = (float*)d_out;

  if (ws_size < WS_CH_BYTES) return;

  bool full = (ws_size >= WS_FULL_BYTES);
  size_t aggfl = full ? FULL_AGG_FL : CH_AGG_FL;
  float* agg  = ws;
  float* wgt  = ws + aggfl;
  float* slut = wgt + WTOT;
  int*   ib   = (int*)(slut + SLUT_N);
  int* cnt  = ib;
  int* offs = ib + NN;
  int* curs = ib + 2*NN + 1;
  int* eids = ib + 3*NN + 1;
  int* bsum  = ib + 3*NN + 1 + NE;
  int* bbase = bsum + 256;

  hipMemsetAsync(cnt, 0, NN*sizeof(int), stream);

  convert_weights<<<(WTOT+255)/256, 256, 0, stream>>>(l1s, l1v, l2s, l2v, wgt);
  build_lut<<<NBINS+1, 128, 0, stream>>>(w1,b1,w2,b2,w3,b3, slut);

  count_kernel<<<(NE+255)/256, 256, 0, stream>>>(rcv, cnt);
  scan_a<<<SCAN_B, 256, 0, stream>>>(cnt, offs, bsum);
  scan_b<<<1, 256, 0, stream>>>(bsum, bbase, offs);
  scan_c<<<SCAN_B, 256, 0, stream>>>(bbase, offs, curs);
  scatter_kernel<<<(NE+255)/256, 256, 0, stream>>>(rcv, curs, eids);

  int nchunks = full ? 1 : 2;
  int csize   = full ? NN : CNN;
  for (int ch = 0; ch < nchunks; ch++){
    int cn0 = ch * csize;
    edge_agg_kernel<<<(csize+3)/4, 256, 0, stream>>>(
        node_scalars, node_vectors, sh, norm, snd, offs, eids, slut,
        agg, cn0, csize);
    node_s_kernel<<<(csize+63)/64, 256, 0, stream>>>(
        node_scalars, wgt, agg, cn0, csize, out);
    node_v_kernel<<<(csize+63)/64, 192, 0, stream>>>(
        node_vectors, wgt, agg, cn0, csize, out);
  }
}

// Round 4
// 349.601 us; speedup vs baseline: 1.6370x; 1.0159x over previous
//
#include <hip/hip_runtime.h>

#define NN 50000
#define NE 400000
#define CNN 25000
#define NBINS 1024

// weight offsets (layout from convert_weights)
#define RL1ST 0            // l1s transposed: (192,64), col-contiguous
#define RL1VT 12288        // l1v transposed: (64,64)
#define RL2S  16384        // l2s original (160,32)
#define RL2V  21504        // l2v original (96,32)
#define WTOT  24576

#define SLUT_N ((NBINS+1)*256)        // 262400
#define N_INTS (3*NN+1+NE+512)        // + bsum/bbase

#define FULL_AGG_FL   ((size_t)NN*256)
#define FULL_TOT_FL   (FULL_AGG_FL + WTOT + SLUT_N + N_INTS)
#define WS_FULL_BYTES (FULL_TOT_FL*4ull)
#define CH_AGG_FL     ((size_t)CNN*256)
#define CH_TOT_FL     (CH_AGG_FL + WTOT + SLUT_N + N_INTS)
#define WS_CH_BYTES   (CH_TOT_FL*4ull)

#define SCAN_B 196                    // ceil(NN/256)

#define S160 0.07905694150420949f
#define S96  0.10206207261596576f

__device__ __forceinline__ float sigf(float x){
  return __builtin_amdgcn_rcpf(1.0f + __expf(-x));
}
__device__ __forceinline__ float siluf(float x){ return x * sigf(x); }

// ---- weights: transpose l1s,l1v; copy l2s,l2v ----
__global__ __launch_bounds__(256) void convert_weights(
    const float* __restrict__ l1s, const float* __restrict__ l1v,
    const float* __restrict__ l2s, const float* __restrict__ l2v,
    float* __restrict__ wgt)
{
  int i = blockIdx.x*256 + threadIdx.x;
  if (i < 12288){ int o=i>>6, m=i&63; wgt[RL1ST + i] = l1s[m*192+o]; return; }
  if (i < 16384){ int t=i-12288; int o=t>>6, m=t&63; wgt[RL1VT + t] = l1v[m*64+o]; return; }
  if (i < 21504){ int t=i-16384; wgt[RL2S + t] = l2s[t]; return; }
  if (i < 24576){ int t=i-21504; wgt[RL2V + t] = l2v[t]; return; }
}

// ---- SLUT[bin][256]: scal(x) at bin edges, per-lane-slot order (c=m*8+q) ----
__global__ __launch_bounds__(128) void build_lut(
    const float* __restrict__ w1, const float* __restrict__ b1,
    const float* __restrict__ w2, const float* __restrict__ b2,
    const float* __restrict__ w3, const float* __restrict__ b3,
    float* __restrict__ slut)
{
  __shared__ float h1[64], h2[64], scal[128];
  int bin = blockIdx.x;            // 0..NBINS
  float x = (float)bin / (float)NBINS;
  int t = threadIdx.x;
  if (t < 64) h1[t] = siluf(fmaf(x, w1[t], b1[t]));
  __syncthreads();
  if (t < 64){
    float a = b2[t];
    for (int k=0;k<64;k++) a = fmaf(h1[k], w2[k*64+t], a);
    h2[t] = siluf(a);
  }
  __syncthreads();
  {
    float a = b3[t];
    for (int k=0;k<64;k++) a = fmaf(h2[k], w3[k*128+t], a);
    scal[t] = a;
  }
  __syncthreads();
  for (int c=t; c<256; c+=128){
    int m=c>>3, q=c&7;
    int idx = (q==0)? m : (q==1)? (32+m) : (q<5)? (64+m) : (96+m);
    slut[(size_t)bin*256 + c] = scal[idx];
  }
}

// ================= CSR build =================
__global__ __launch_bounds__(256) void count_kernel(
    const int* __restrict__ rcv, int* __restrict__ cnt)
{
  int e = blockIdx.x*256 + threadIdx.x;
  if (e < NE) atomicAdd(&cnt[rcv[e]], 1);
}

// multi-block scan, stage A: block-local exclusive scan + block sums
__global__ __launch_bounds__(256) void scan_a(
    const int* __restrict__ cnt, int* __restrict__ offs, int* __restrict__ bsum)
{
  __shared__ int sd[256];
  int tid = threadIdx.x;
  int i = blockIdx.x*256 + tid;
  int c = (i < NN) ? cnt[i] : 0;
  sd[tid] = c;
  __syncthreads();
  for (int off=1; off<256; off<<=1){
    int t = (tid >= off) ? sd[tid-off] : 0;
    __syncthreads();
    sd[tid] += t;
    __syncthreads();
  }
  if (i < NN) offs[i] = sd[tid] - c;          // local exclusive
  if (tid == 255) bsum[blockIdx.x] = sd[255]; // block total
}

// stage B: scan of block sums (196 values), also writes offs[NN]=total
__global__ __launch_bounds__(256) void scan_b(
    const int* __restrict__ bsum, int* __restrict__ bbase, int* __restrict__ offs)
{
  __shared__ int sd[256];
  int tid = threadIdx.x;
  int v = (tid < SCAN_B) ? bsum[tid] : 0;
  sd[tid] = v;
  __syncthreads();
  for (int off=1; off<256; off<<=1){
    int t = (tid >= off) ? sd[tid-off] : 0;
    __syncthreads();
    sd[tid] += t;
    __syncthreads();
  }
  if (tid < SCAN_B) bbase[tid] = sd[tid] - v;
  if (tid == 255) offs[NN] = sd[255];
}

// stage C: add block base, init cursors
__global__ __launch_bounds__(256) void scan_c(
    const int* __restrict__ bbase, int* __restrict__ offs, int* __restrict__ curs)
{
  int i = blockIdx.x*256 + threadIdx.x;
  if (i < NN){
    int o = offs[i] + bbase[blockIdx.x];
    offs[i] = o;
    curs[i] = o;
  }
}

__global__ __launch_bounds__(256) void scatter_kernel(
    const int* __restrict__ rcv, int* __restrict__ curs, int* __restrict__ eids)
{
  int e = blockIdx.x*256 + threadIdx.x;
  if (e >= NE) return;
  int pos = atomicAdd(&curs[rcv[e]], 1);
  eids[pos] = e;
}

// ================= Edge+aggregate: wave per node, lane per 4 comps =========
// Output layout: agg[node][c'] with c' = block*32 + m:
//   block0: y0*s (scal m)      block1: dot (scal 32+m)
//   block2: y0*v0   block3: y1_0*s   (aggv k=0)
//   block4: y0*v1   block5: y1_1*s   (aggv k=1)
//   block6: y0*v2   block7: y1_2*s   (aggv k=2)
// 3-stage software pipeline: meta(p+2) || heavy-loads(p+1) || compute(p).
__global__ __launch_bounds__(256) void edge_agg_kernel(
    const float* __restrict__ ns, const float* __restrict__ nv,
    const float* __restrict__ sh, const float* __restrict__ nrm,
    const int* __restrict__ snd,
    const int* __restrict__ offs, const int* __restrict__ eids,
    const float* __restrict__ slut,
    float* __restrict__ agg, int cn0, int cnn)
{
  int wave = threadIdx.x >> 6;
  int lane = threadIdx.x & 63;
  int nl = blockIdx.x*4 + wave;
  if (nl >= cnn) return;
  int n = cn0 + nl;
  int m = lane >> 1;
  int odd = lane & 1;
  int p0 = offs[n], p1 = offs[n+1];
  const float4* slut4 = (const float4*)slut;
  const float inv_sqrt3 = 0.57735026918962576f;
  float a0=0.f, a1=0.f, a2=0.f, a3=0.f;

  if (p0 < p1){
    const int plast = p1 - 1;
    // --- prologue: meta(p0) ---
    int e0 = eids[p0];
    int s0 = snd[e0];
    float x0 = nrm[e0];
    float4 y0 = *(const float4*)(sh + 4*e0);
    // --- B(p0): heavy loads ---
    float f0 = fminf(fmaxf(x0*(float)NBINS, 0.0f), (float)NBINS - 0.001f);
    int bin0 = (int)f0;
    float tt0 = f0 - (float)bin0;
    float4 La = slut4[(size_t)bin0*64 + lane];
    float4 Lb = slut4[(size_t)(bin0+1)*64 + lane];
    float se0 = ns[(size_t)s0*32 + m];
    const float* vp0 = nv + (size_t)s0*96 + 3*m;
    float v00 = vp0[0], v01 = vp0[1], v02 = vp0[2];
    // --- meta(p0+1) ---
    int pm = (p0+1 <= plast) ? (p0+1) : plast;
    int e1 = eids[pm];
    int s1 = snd[e1];
    float x1 = nrm[e1];
    float4 y1 = *(const float4*)(sh + 4*e1);

    for (int p = p0; p <= plast; ++p){
      // issue meta(p+2)
      int pn = (p+2 <= plast) ? (p+2) : plast;
      int e2 = eids[pn];
      int s2 = snd[e2];
      float x2 = nrm[e2];
      float4 y2 = *(const float4*)(sh + 4*e2);
      // issue B(p+1) from meta(p+1)
      float f1 = fminf(fmaxf(x1*(float)NBINS, 0.0f), (float)NBINS - 0.001f);
      int bin1 = (int)f1;
      float tt1 = f1 - (float)bin1;
      float4 La1 = slut4[(size_t)bin1*64 + lane];
      float4 Lb1 = slut4[(size_t)(bin1+1)*64 + lane];
      float se1 = ns[(size_t)s1*32 + m];
      const float* vp1 = nv + (size_t)s1*96 + 3*m;
      float v10 = vp1[0], v11 = vp1[1], v12 = vp1[2];

      // compute C(p) from B(p) (loaded one iteration ago)
      float sc0 = fmaf(tt0, Lb.x-La.x, La.x);
      float sc1 = fmaf(tt0, Lb.y-La.y, La.y);
      float sc2 = fmaf(tt0, Lb.z-La.z, La.z);
      float sc3 = fmaf(tt0, Lb.w-La.w, La.w);
      float A0,A1,A2,A3;
      if (!odd){
        float dot = fmaf(y0.w, v02, fmaf(y0.z, v01, y0.y*v00));
        A0 = y0.x*se0; A1 = dot*inv_sqrt3; A2 = y0.x*v00; A3 = y0.x*v01;
      } else {
        A0 = y0.x*v02; A1 = y0.y*se0; A2 = y0.z*se0; A3 = y0.w*se0;
      }
      a0 = fmaf(A0, sc0, a0);
      a1 = fmaf(A1, sc1, a1);
      a2 = fmaf(A2, sc2, a2);
      a3 = fmaf(A3, sc3, a3);

      // rotate pipeline registers
      y0 = y1; tt0 = tt1;
      La = La1; Lb = Lb1;
      se0 = se1; v00 = v10; v01 = v11; v02 = v12;
      s1 = s2; x1 = x2; y1 = y2;
    }
  }
  int deg = p1 - p0;
  float inv = (deg > 0) ? __builtin_amdgcn_rcpf((float)deg) : 1.0f;
  float* ap = agg + (size_t)nl*256;
  int pos0 = odd ? (192+m) : m;        // q4 : q0
  int pos1 = odd ? ( 96+m) : (32+m);   // q5 : q1
  int pos2 = odd ? (160+m) : (64+m);   // q6 : q2
  int pos3 = odd ? (224+m) : (128+m);  // q7 : q3
  ap[pos0] = a0*inv;
  ap[pos1] = a1*inv;
  ap[pos2] = a2*inv;
  ap[pos3] = a3*inv;
}

// ================= Node phase: no weight staging, contiguous agg slices ====
// Kernel S: lane=node, 4 roles x (32 act cols + 8 ns rows) -> partial oacc,
// single-round LDS reduce, role0 writes out[:,0:32].
__global__ __launch_bounds__(256) __attribute__((amdgpu_waves_per_eu(3,8)))
void node_s_kernel(
    const float* __restrict__ ns, const float* __restrict__ wgt,
    const float* __restrict__ agg, int cn0, int cnn,
    float* __restrict__ out)
{
  __shared__ float red[3*64*33];     // 25.3 KB
  int lane = threadIdx.x & 63, role = threadIdx.x >> 6;
  int ro = __builtin_amdgcn_readfirstlane(role);
  int nl = blockIdx.x*64 + lane;
  bool valid = (nl < cnn);
  int nls = valid ? nl : (cnn-1);
  int n = cn0 + nl;

  float aggs[64];
  float oacc[32];
  #pragma unroll
  for (int j=0;j<32;j++) oacc[j]=0.0f;

  {
    const float4* ar = (const float4*)(agg + (size_t)nls*256);
    #pragma unroll
    for (int g=0; g<16; g++){
      float4 v = ar[g];
      aggs[4*g+0]=v.x; aggs[4*g+1]=v.y; aggs[4*g+2]=v.z; aggs[4*g+3]=v.w;
    }
  }
  // 32 act columns for this role
  const float* l1sT = wgt + RL1ST + ro*32*64;
  const float* l2s  = wgt + RL2S;
  for (int t=0;t<32;t++){
    const float4* col = (const float4*)(l1sT + t*64);
    float d0=0,d1=0,d2=0,d3=0;
    #pragma unroll
    for (int j=0;j<16;j++){
      float4 c = col[j];
      d0 = fmaf(aggs[4*j+0], c.x, d0);
      d1 = fmaf(aggs[4*j+1], c.y, d1);
      d2 = fmaf(aggs[4*j+2], c.z, d2);
      d3 = fmaf(aggs[4*j+3], c.w, d3);
    }
    float act = siluf(((d0+d1)+(d2+d3))*0.125f);
    const float4* row = (const float4*)(l2s + (size_t)(ro*32 + t)*32);
    #pragma unroll
    for (int j=0;j<8;j++){
      float4 w = row[j];
      oacc[4*j+0] = fmaf(act, w.x, oacc[4*j+0]);
      oacc[4*j+1] = fmaf(act, w.y, oacc[4*j+1]);
      oacc[4*j+2] = fmaf(act, w.z, oacc[4*j+2]);
      oacc[4*j+3] = fmaf(act, w.w, oacc[4*j+3]);
    }
  }
  // ns part: this role's 8 q rows (c_s rows 128+q)
  {
    const float4* sp = (const float4*)(ns + (size_t)(cn0+nls)*32 + ro*8);
    #pragma unroll
    for (int q4=0;q4<2;q4++){
      float4 v = sp[q4];
      float vv[4] = {v.x, v.y, v.z, v.w};
      #pragma unroll
      for (int u=0;u<4;u++){
        int q = ro*8 + q4*4 + u;
        const float4* row = (const float4*)(l2s + (size_t)(128+q)*32);
        #pragma unroll
        for (int j=0;j<8;j++){
          float4 w = row[j];
          oacc[4*j+0] = fmaf(vv[u], w.x, oacc[4*j+0]);
          oacc[4*j+1] = fmaf(vv[u], w.y, oacc[4*j+1]);
          oacc[4*j+2] = fmaf(vv[u], w.z, oacc[4*j+2]);
          oacc[4*j+3] = fmaf(vv[u], w.w, oacc[4*j+3]);
        }
      }
    }
  }

  // single-round reduce into role 0
  if (role != 0){
    float* rp = red + (role-1)*(64*33) + lane*33;
    #pragma unroll
    for (int j=0;j<32;j++) rp[j] = oacc[j];
  }
  __syncthreads();
  if (role == 0 && valid){
    #pragma unroll
    for (int j=0;j<32;j++)
      oacc[j] += red[0*(64*33)+lane*33+j] + red[1*(64*33)+lane*33+j]
               + red[2*(64*33)+lane*33+j];
    float4* op = (float4*)(out + (size_t)n*128);
    #pragma unroll
    for (int j=0;j<8;j++){
      float4 o4;
      o4.x = oacc[4*j+0]*S160; o4.y = oacc[4*j+1]*S160;
      o4.z = oacc[4*j+2]*S160; o4.w = oacc[4*j+3]*S160;
      op[j] = o4;
    }
  }
}

// Kernel V: lane=node, 3 waves. Phase A: gates -> LDS. Phase B: wave k owns
// vector component k. Output staged in LDS (rows padded to 97), coalesced write.
__global__ __launch_bounds__(192) __attribute__((amdgpu_waves_per_eu(3,8)))
void node_v_kernel(
    const float* __restrict__ nv, const float* __restrict__ wgt,
    const float* __restrict__ agg, int cn0, int cnn,
    float* __restrict__ out)
{
  __shared__ float sw[64*97];        // 24.8 KB (sgate uses first 4096 floats)
  int lane = threadIdx.x & 63, role = threadIdx.x >> 6;  // role 0..2
  int ro = __builtin_amdgcn_readfirstlane(role);
  int nl = blockIdx.x*64 + lane;
  bool valid = (nl < cnn);
  int nls = valid ? nl : (cnn-1);
  const float* arow = agg + (size_t)nls*256;

  // ---- Phase A: gates ----
  {
    float aggs[64];
    const float4* ar = (const float4*)arow;
    #pragma unroll
    for (int g=0; g<16; g++){
      float4 v = ar[g];
      aggs[4*g+0]=v.x; aggs[4*g+1]=v.y; aggs[4*g+2]=v.z; aggs[4*g+3]=v.w;
    }
    const float* l1g = wgt + RL1ST + 128*64;     // gate cols 128..191
    for (int o=ro; o<64; o+=3){
      const float4* col = (const float4*)(l1g + o*64);
      float d0=0,d1=0,d2=0,d3=0;
      #pragma unroll
      for (int j=0;j<16;j++){
        float4 c = col[j];
        d0 = fmaf(aggs[4*j+0], c.x, d0);
        d1 = fmaf(aggs[4*j+1], c.y, d1);
        d2 = fmaf(aggs[4*j+2], c.z, d2);
        d3 = fmaf(aggs[4*j+3], c.w, d3);
      }
      sw[o*64+lane] = sigf(((d0+d1)+(d2+d3))*0.125f);
    }
  }
  __syncthreads();

  // ---- Phase B: component k = role ----
  int k = role;
  float aggv[64], oacc[32];
  #pragma unroll
  for (int j=0;j<32;j++) oacc[j]=0.0f;
  {
    const float4* av = (const float4*)(arow + 64 + 64*k);
    #pragma unroll
    for (int g=0; g<16; g++){
      float4 v = av[g];
      aggv[4*g+0]=v.x; aggv[4*g+1]=v.y; aggv[4*g+2]=v.z; aggv[4*g+3]=v.w;
    }
  }
  const float* l1vT = wgt + RL1VT;
  const float* l2v  = wgt + RL2V;
  for (int o=0;o<64;o++){
    const float4* col = (const float4*)(l1vT + o*64);
    float d0=0,d1=0,d2=0,d3=0;
    #pragma unroll
    for (int j=0;j<16;j++){
      float4 c = col[j];
      d0 = fmaf(aggv[4*j+0], c.x, d0);
      d1 = fmaf(aggv[4*j+1], c.y, d1);
      d2 = fmaf(aggv[4*j+2], c.z, d2);
      d3 = fmaf(aggv[4*j+3], c.w, d3);
    }
    float gv = (((d0+d1)+(d2+d3))*0.125f) * sw[o*64+lane];
    const float4* row = (const float4*)(l2v + (size_t)o*32);
    #pragma unroll
    for (int j=0;j<8;j++){
      float4 w = row[j];
      oacc[4*j+0] = fmaf(gv, w.x, oacc[4*j+0]);
      oacc[4*j+1] = fmaf(gv, w.y, oacc[4*j+1]);
      oacc[4*j+2] = fmaf(gv, w.z, oacc[4*j+2]);
      oacc[4*j+3] = fmaf(gv, w.w, oacc[4*j+3]);
    }
  }
  {
    const float* vp = nv + (size_t)(cn0+nls)*96 + k;
    #pragma unroll 8
    for (int q=0;q<32;q++){
      float a = vp[3*q];
      const float4* row = (const float4*)(l2v + (size_t)(64+q)*32);
      #pragma unroll
      for (int j=0;j<8;j++){
        float4 w = row[j];
        oacc[4*j+0] = fmaf(a, w.x, oacc[4*j+0]);
        oacc[4*j+1] = fmaf(a, w.y, oacc[4*j+1]);
        oacc[4*j+2] = fmaf(a, w.z, oacc[4*j+2]);
        oacc[4*j+3] = fmaf(a, w.w, oacc[4*j+3]);
      }
    }
  }

  // ---- stage outputs in LDS (rows padded to 97), then coalesced write ----
  __syncthreads();          // done reading sgate region
  if (valid){
    #pragma unroll
    for (int j=0;j<32;j++) sw[lane*97 + 3*j + k] = oacc[j]*S96;
  }
  __syncthreads();
  int nb = blockIdx.x*64;
  #pragma unroll
  for (int r=0;r<8;r++){
    int F = r*192 + threadIdx.x;       // 0..1535 -> 64 nodes x 24 float4
    int i = F/24, j = F%24;
    if (nb + i < cnn){
      float4 o4;
      o4.x = sw[i*97 + 4*j + 0];
      o4.y = sw[i*97 + 4*j + 1];
      o4.z = sw[i*97 + 4*j + 2];
      o4.w = sw[i*97 + 4*j + 3];
      *(float4*)(out + (size_t)(cn0+nb+i)*128 + 32 + 4*j) = o4;
    }
  }
}

extern "C" void kernel_launch(void* const* d_in, const int* in_sizes, int n_in,
                              void* d_out, int out_size, void* d_ws, size_t ws_size,
                              hipStream_t stream) {
  const float* node_scalars = (const float*)d_in[0];
  const float* node_vectors = (const float*)d_in[1];
  const float* sh           = (const float*)d_in[2];
  const float* norm         = (const float*)d_in[3];
  const float* w1  = (const float*)d_in[4];
  const float* b1  = (const float*)d_in[5];
  const float* w2  = (const float*)d_in[6];
  const float* b2  = (const float*)d_in[7];
  const float* w3  = (const float*)d_in[8];
  const float* b3  = (const float*)d_in[9];
  const float* l1s = (const float*)d_in[10];
  const float* l1v = (const float*)d_in[11];
  const float* l2s = (const float*)d_in[12];
  const float* l2v = (const float*)d_in[13];
  const int* snd = (const int*)d_in[14];
  const int* rcv = (const int*)d_in[15];
  float* ws = (float*)d_ws;
  float* out = (float*)d_out;

  if (ws_size < WS_CH_BYTES) return;

  bool full = (ws_size >= WS_FULL_BYTES);
  size_t aggfl = full ? FULL_AGG_FL : CH_AGG_FL;
  float* agg  = ws;
  float* wgt  = ws + aggfl;
  float* slut = wgt + WTOT;
  int*   ib   = (int*)(slut + SLUT_N);
  int* cnt  = ib;
  int* offs = ib + NN;
  int* curs = ib + 2*NN + 1;
  int* eids = ib + 3*NN + 1;
  int* bsum  = ib + 3*NN + 1 + NE;
  int* bbase = bsum + 256;

  hipMemsetAsync(cnt, 0, NN*sizeof(int), stream);

  convert_weights<<<(WTOT+255)/256, 256, 0, stream>>>(l1s, l1v, l2s, l2v, wgt);
  build_lut<<<NBINS+1, 128, 0, stream>>>(w1,b1,w2,b2,w3,b3, slut);

  count_kernel<<<(NE+255)/256, 256, 0, stream>>>(rcv, cnt);
  scan_a<<<SCAN_B, 256, 0, stream>>>(cnt, offs, bsum);
  scan_b<<<1, 256, 0, stream>>>(bsum, bbase, offs);
  scan_c<<<SCAN_B, 256, 0, stream>>>(bbase, offs, curs);
  scatter_kernel<<<(NE+255)/256, 256, 0, stream>>>(rcv, curs, eids);

  int nchunks = full ? 1 : 2;
  int csize   = full ? NN : CNN;
  for (int ch = 0; ch < nchunks; ch++){
    int cn0 = ch * csize;
    edge_agg_kernel<<<(csize+3)/4, 256, 0, stream>>>(
        node_scalars, node_vectors, sh, norm, snd, offs, eids, slut,
        agg, cn0, csize);
    node_s_kernel<<<(csize+63)/64, 256, 0, stream>>>(
        node_scalars, wgt, agg, cn0, csize, out);
    node_v_kernel<<<(csize+63)/64, 192, 0, stream>>>(
        node_vectors, wgt, agg, cn0, csize, out);
  }
}